// Round 3
// baseline (358.112 us; speedup 1.0000x reference)
//
#include <hip/hip_runtime.h>

#define TT 512
#define HH 32

typedef _Float16 half2_t __attribute__((ext_vector_type(2)));

__device__ __forceinline__ float fast_exp2(float v) { return __builtin_amdgcn_exp2f(v); }
__device__ __forceinline__ float fast_rcp(float v)  { return __builtin_amdgcn_rcpf(v); }

// sigmoid(x) = 1/(1+exp2(-log2e * x))
__device__ __forceinline__ float sigmoid_f(float v) {
    return fast_rcp(1.0f + fast_exp2(-1.442695040888963f * v));
}
// tanh(x) = 2/(1+exp2(-2*log2e*x)) - 1
__device__ __forceinline__ float tanh_f(float v) {
    return __builtin_fmaf(2.0f, fast_rcp(1.0f + fast_exp2(-2.885390081777927f * v)), -1.0f);
}

__device__ __forceinline__ half2_t u2h(unsigned int u) {
    return __builtin_bit_cast(half2_t, u);
}

__global__ __launch_bounds__(256, 4) void lstm_fused_kernel(
    const float* __restrict__ x,     // [B, T, 1]
    const float* __restrict__ wih,   // [128, 1]
    const float* __restrict__ whh,   // [128, 32]
    const float* __restrict__ bih,   // [128]
    const float* __restrict__ bhh,   // [128]
    const float* __restrict__ fc1w,  // [16, 32]
    const float* __restrict__ fc1b,  // [16]
    const float* __restrict__ fc2w,  // [1, 16]
    const float* __restrict__ fc2b,  // [1]
    float* __restrict__ out)         // [B, 1]
{
    __shared__ float lds_x[4][TT];

    const int wave = threadIdx.x >> 6;
    const int lane = threadIdx.x & 63;
    const int b = blockIdx.x * 4 + wave;

    // ---- stage x[b][0..511] into LDS (coalesced float4) ----
    {
        const float4* xv = reinterpret_cast<const float4*>(x + (size_t)b * TT);
        float4* lv = reinterpret_cast<float4*>(&lds_x[wave][0]);
        lv[lane]      = xv[lane];       // floats [0..255]
        lv[lane + 64] = xv[lane + 64];  // floats [256..511]
    }

    // ---- per-lane gate rows: g0 = lane (i/f rows), g1 = lane+64 (g/o rows) ----
    const int g0 = lane;
    const int g1 = lane + 64;

    // load W_hh rows, convert to packed fp16 words; pin in VGPRs with opaque asm
    unsigned int w0u[16], w1u[16];
    {
        const float4* r0 = reinterpret_cast<const float4*>(whh + g0 * HH);
        const float4* r1 = reinterpret_cast<const float4*>(whh + g1 * HH);
#pragma unroll
        for (int k4 = 0; k4 < 8; ++k4) {
            float4 a = r0[k4];
            half2_t p0; p0[0] = (_Float16)a.x; p0[1] = (_Float16)a.y;
            half2_t p1; p1[0] = (_Float16)a.z; p1[1] = (_Float16)a.w;
            w0u[k4 * 2 + 0] = __builtin_bit_cast(unsigned int, p0);
            w0u[k4 * 2 + 1] = __builtin_bit_cast(unsigned int, p1);
            float4 bb = r1[k4];
            half2_t q0; q0[0] = (_Float16)bb.x; q0[1] = (_Float16)bb.y;
            half2_t q1; q1[0] = (_Float16)bb.z; q1[1] = (_Float16)bb.w;
            w1u[k4 * 2 + 0] = __builtin_bit_cast(unsigned int, q0);
            w1u[k4 * 2 + 1] = __builtin_bit_cast(unsigned int, q1);
        }
    }
#pragma unroll
    for (int k = 0; k < 16; ++k) {
        asm volatile("" : "+v"(w0u[k]));
        asm volatile("" : "+v"(w1u[k]));
    }

    const float wi0   = wih[g0];
    const float wi1   = wih[g1];
    const float bias0 = bih[g0] + bhh[g0];
    const float bias1 = bih[g1] + bhh[g1];

    const bool lo = (lane < HH);
    // branch-free activation constants for gate1: lanes<32 -> tanh(g), lanes>=32 -> sigmoid(o)
    const float kk = lo ? -2.885390081777927f : -1.442695040888963f;
    const float sc = lo ? 2.0f : 1.0f;
    const float ad = lo ? -1.0f : 0.0f;

    // h state: wave-uniform packed fp16 pairs (kept in SGPRs via readlane)
    unsigned int hh_u[16];
#pragma unroll
    for (int k = 0; k < 16; ++k) hh_u[k] = 0u;

    float c = 0.0f;

    __syncthreads();

#pragma unroll 1
    for (int t = 0; t < TT; ++t) {
        const float xt = lds_x[wave][t];  // broadcast read
        float acc0 = __builtin_fmaf(xt, wi0, bias0);
        float acc1 = __builtin_fmaf(xt, wi1, bias1);
#pragma unroll
        for (int k = 0; k < 16; ++k) {
            acc0 = __builtin_amdgcn_fdot2(u2h(hh_u[k]), u2h(w0u[k]), acc0, false);
            acc1 = __builtin_amdgcn_fdot2(u2h(hh_u[k]), u2h(w1u[k]), acc1, false);
        }

        // activations: acc0 is always a sigmoid gate (i for lanes<32, f for lanes>=32)
        const float a0 = sigmoid_f(acc0);
        const float a1 = __builtin_fmaf(sc, fast_rcp(1.0f + fast_exp2(kk * acc1)), ad);

        // exchange halves: lane j <-> lane j+32
        const float p0 = __shfl_xor(a0, 32);
        const float p1 = __shfl_xor(a1, 32);
        const float i_ = lo ? a0 : p0;
        const float f_ = lo ? p0 : a0;
        const float g_ = lo ? a1 : p1;
        const float o_ = lo ? p1 : a1;

        c = __builtin_fmaf(f_, c, i_ * g_);
        const float hn = o_ * tanh_f(c);

        // pack (h[2m], h[2m+1]) into one 32-bit word in even lanes, then
        // broadcast to SGPRs via readlane (h is wave-uniform state)
        _Float16 hf = (_Float16)hn;
        unsigned int hu = (unsigned int)__builtin_bit_cast(unsigned short, hf);
        unsigned int hun = (unsigned int)__shfl_xor((int)hu, 1);
        unsigned int packed = hu | (hun << 16);
#pragma unroll
        for (int k = 0; k < 16; ++k) {
            hh_u[k] = (unsigned int)__builtin_amdgcn_readlane((int)packed, 2 * k);
        }
    }

    // ---- final h (fp32) from the wave-uniform packed state ----
    float hfin[HH];
#pragma unroll
    for (int k = 0; k < 16; ++k) {
        half2_t h2 = u2h(hh_u[k]);
        hfin[2 * k + 0] = (float)h2[0];
        hfin[2 * k + 1] = (float)h2[1];
    }

    // ---- MLP head: z = relu(h@fc1w.T + fc1b); out = z@fc2w.T + fc2b ----
    float val = 0.0f;
    if (lane < 16) {
        float acc = fc1b[lane];
#pragma unroll
        for (int j = 0; j < HH; ++j) acc = __builtin_fmaf(hfin[j], fc1w[lane * HH + j], acc);
        val = fmaxf(acc, 0.0f) * fc2w[lane];
    }
#pragma unroll
    for (int off = 8; off; off >>= 1) val += __shfl_down(val, off);
    if (lane == 0) out[b] = val + fc2b[0];
}

extern "C" void kernel_launch(void* const* d_in, const int* in_sizes, int n_in,
                              void* d_out, int out_size, void* d_ws, size_t ws_size,
                              hipStream_t stream) {
    const float* x    = (const float*)d_in[0];
    const float* wih  = (const float*)d_in[1];
    const float* whh  = (const float*)d_in[2];
    const float* bih  = (const float*)d_in[3];
    const float* bhh  = (const float*)d_in[4];
    const float* fc1w = (const float*)d_in[5];
    const float* fc1b = (const float*)d_in[6];
    const float* fc2w = (const float*)d_in[7];
    const float* fc2b = (const float*)d_in[8];
    float* out = (float*)d_out;

    const int B = out_size;            // 4096
    dim3 grid(B / 4), block(256);
    hipLaunchKernelGGL(lstm_fused_kernel, grid, block, 0, stream,
                       x, wih, whh, bih, bhh, fc1w, fc1b, fc2w, fc2b, out);
}

// Round 4
// 271.978 us; speedup vs baseline: 1.3167x; 1.3167x over previous
//
#include <hip/hip_runtime.h>

#define TT 512
#define HH 32

typedef _Float16 half2_t __attribute__((ext_vector_type(2)));

__device__ __forceinline__ float fast_exp2(float v) { return __builtin_amdgcn_exp2f(v); }
__device__ __forceinline__ float fast_rcp(float v)  { return __builtin_amdgcn_rcpf(v); }

// sigmoid(x) = 1/(1+exp2(-log2e * x))
__device__ __forceinline__ float sigmoid_f(float v) {
    return fast_rcp(1.0f + fast_exp2(-1.442695040888963f * v));
}

__device__ __forceinline__ half2_t u2h(unsigned int u) {
    return __builtin_bit_cast(half2_t, u);
}

__global__ __launch_bounds__(256, 4) void lstm_fused_kernel(
    const float* __restrict__ x,     // [B, T, 1]
    const float* __restrict__ wih,   // [128, 1]
    const float* __restrict__ whh,   // [128, 32]
    const float* __restrict__ bih,   // [128]
    const float* __restrict__ bhh,   // [128]
    const float* __restrict__ fc1w,  // [16, 32]
    const float* __restrict__ fc1b,  // [16]
    const float* __restrict__ fc2w,  // [1, 16]
    const float* __restrict__ fc2b,  // [1]
    float* __restrict__ out)         // [B, 1]
{
    __shared__ float    lds_x[4][TT];
    __shared__ _Float16 lds_h[4][64];   // per-wave h broadcast buffer (first 32 used)

    const int wave = threadIdx.x >> 6;
    const int lane = threadIdx.x & 63;
    const int b = blockIdx.x * 4 + wave;

    // ---- stage x[b][0..511] into LDS (coalesced float4) ----
    {
        const float4* xv = reinterpret_cast<const float4*>(x + (size_t)b * TT);
        float4* lv = reinterpret_cast<float4*>(&lds_x[wave][0]);
        lv[lane]      = xv[lane];       // floats [0..255]
        lv[lane + 64] = xv[lane + 64];  // floats [256..511]
    }

    // ---- per-lane gate rows: g0 = lane (i/f rows), g1 = lane+64 (g/o rows) ----
    const int g0 = lane;
    const int g1 = lane + 64;

    // load W_hh rows, convert to packed fp16 words; pin in VGPRs with opaque asm
    unsigned int w0u[16], w1u[16];
    {
        const float4* r0 = reinterpret_cast<const float4*>(whh + g0 * HH);
        const float4* r1 = reinterpret_cast<const float4*>(whh + g1 * HH);
#pragma unroll
        for (int k4 = 0; k4 < 8; ++k4) {
            float4 a = r0[k4];
            half2_t p0; p0[0] = (_Float16)a.x; p0[1] = (_Float16)a.y;
            half2_t p1; p1[0] = (_Float16)a.z; p1[1] = (_Float16)a.w;
            w0u[k4 * 2 + 0] = __builtin_bit_cast(unsigned int, p0);
            w0u[k4 * 2 + 1] = __builtin_bit_cast(unsigned int, p1);
            float4 bb = r1[k4];
            half2_t q0; q0[0] = (_Float16)bb.x; q0[1] = (_Float16)bb.y;
            half2_t q1; q1[0] = (_Float16)bb.z; q1[1] = (_Float16)bb.w;
            w1u[k4 * 2 + 0] = __builtin_bit_cast(unsigned int, q0);
            w1u[k4 * 2 + 1] = __builtin_bit_cast(unsigned int, q1);
        }
    }
#pragma unroll
    for (int k = 0; k < 16; ++k) {
        asm volatile("" : "+v"(w0u[k]));
        asm volatile("" : "+v"(w1u[k]));
    }

    const float wi0   = wih[g0];
    const float wi1   = wih[g1];
    const float bias0 = bih[g0] + bhh[g0];
    const float bias1 = bih[g1] + bhh[g1];

    const bool lo = (lane < HH);
    // branch-free activation constants for gate1: lanes<32 -> tanh(g), lanes>=32 -> sigmoid(o)
    const float kk = lo ? -2.885390081777927f : -1.442695040888963f;
    const float sc = lo ? 2.0f : 1.0f;
    const float ad = lo ? -1.0f : 0.0f;

    // h == 0 initially: every lane zeroes its slot (covers all 128 bytes)
    lds_h[wave][lane] = (_Float16)0.0f;

    float c = 0.0f;

    __syncthreads();

#pragma unroll 1
    for (int t = 0; t < TT; ++t) {
        // broadcast-read packed h (uniform addresses -> conflict-free)
        unsigned int hh_u[16];
        {
            const uint4* hp = reinterpret_cast<const uint4*>(&lds_h[wave][0]);
            uint4 q0 = hp[0];
            uint4 q1 = hp[1];
            uint4 q2 = hp[2];
            uint4 q3 = hp[3];
            hh_u[0]  = q0.x; hh_u[1]  = q0.y; hh_u[2]  = q0.z; hh_u[3]  = q0.w;
            hh_u[4]  = q1.x; hh_u[5]  = q1.y; hh_u[6]  = q1.z; hh_u[7]  = q1.w;
            hh_u[8]  = q2.x; hh_u[9]  = q2.y; hh_u[10] = q2.z; hh_u[11] = q2.w;
            hh_u[12] = q3.x; hh_u[13] = q3.y; hh_u[14] = q3.z; hh_u[15] = q3.w;
        }

        const float xt = lds_x[wave][t];  // broadcast read
        float acc0 = __builtin_fmaf(xt, wi0, bias0);
        float acc1 = __builtin_fmaf(xt, wi1, bias1);
#pragma unroll
        for (int k = 0; k < 16; ++k) {
            acc0 = __builtin_amdgcn_fdot2(u2h(hh_u[k]), u2h(w0u[k]), acc0, false);
            acc1 = __builtin_amdgcn_fdot2(u2h(hh_u[k]), u2h(w1u[k]), acc1, false);
        }

        // activations: acc0 is always a sigmoid gate (i for lanes<32, f for lanes>=32)
        const float a0 = sigmoid_f(acc0);
        const float a1 = __builtin_fmaf(sc, fast_rcp(1.0f + fast_exp2(kk * acc1)), ad);

        // exchange halves: lane j <-> lane j+32
        const float p0 = __shfl_xor(a0, 32);
        const float p1 = __shfl_xor(a1, 32);
        const float i_ = lo ? a0 : p0;
        const float f_ = lo ? p0 : a0;
        const float g_ = lo ? a1 : p1;
        const float o_ = lo ? p1 : a1;

        c = __builtin_fmaf(f_, c, i_ * g_);
        // h = o*tanh(c) = 2o*rcp(1+exp2(-2*log2e*c)) - o
        const float e  = fast_exp2(-2.885390081777927f * c);
        const float hn = __builtin_fmaf(2.0f * o_, fast_rcp(1.0f + e), -o_);

        // every lane writes its own fp16 h at 2*lane (lanes 32..63 write dup
        // values to bytes 64..127, harmless); next-iter reads use bytes 0..63
        lds_h[wave][lane] = (_Float16)hn;
    }

    // ---- final h (fp32) from LDS (written on last iteration) ----
    float hfin[HH];
    {
        const uint4* hp = reinterpret_cast<const uint4*>(&lds_h[wave][0]);
        uint4 q0 = hp[0];
        uint4 q1 = hp[1];
        uint4 q2 = hp[2];
        uint4 q3 = hp[3];
        unsigned int w[16] = {q0.x,q0.y,q0.z,q0.w, q1.x,q1.y,q1.z,q1.w,
                              q2.x,q2.y,q2.z,q2.w, q3.x,q3.y,q3.z,q3.w};
#pragma unroll
        for (int k = 0; k < 16; ++k) {
            half2_t h2 = u2h(w[k]);
            hfin[2 * k + 0] = (float)h2[0];
            hfin[2 * k + 1] = (float)h2[1];
        }
    }

    // ---- MLP head: z = relu(h@fc1w.T + fc1b); out = z@fc2w.T + fc2b ----
    float val = 0.0f;
    if (lane < 16) {
        float acc = fc1b[lane];
#pragma unroll
        for (int j = 0; j < HH; ++j) acc = __builtin_fmaf(hfin[j], fc1w[lane * HH + j], acc);
        val = fmaxf(acc, 0.0f) * fc2w[lane];
    }
#pragma unroll
    for (int off = 8; off; off >>= 1) val += __shfl_down(val, off);
    if (lane == 0) out[b] = val + fc2b[0];
}

extern "C" void kernel_launch(void* const* d_in, const int* in_sizes, int n_in,
                              void* d_out, int out_size, void* d_ws, size_t ws_size,
                              hipStream_t stream) {
    const float* x    = (const float*)d_in[0];
    const float* wih  = (const float*)d_in[1];
    const float* whh  = (const float*)d_in[2];
    const float* bih  = (const float*)d_in[3];
    const float* bhh  = (const float*)d_in[4];
    const float* fc1w = (const float*)d_in[5];
    const float* fc1b = (const float*)d_in[6];
    const float* fc2w = (const float*)d_in[7];
    const float* fc2b = (const float*)d_in[8];
    float* out = (float*)d_out;

    const int B = out_size;            // 4096
    dim3 grid(B / 4), block(256);
    hipLaunchKernelGGL(lstm_fused_kernel, grid, block, 0, stream,
                       x, wih, whh, bih, bhh, fc1w, fc1b, fc2w, fc2b, out);
}